// Round 8
// baseline (879.943 us; speedup 1.0000x reference)
//
#include <hip/hip_runtime.h>
#include <hip/hip_bf16.h>

// Problem constants
#define NB    32
#define DIM   512
#define HEADS 8
#define HD    64
#define NPIX  1024   // H*W = 32*32

typedef __bf16 bf16x8 __attribute__((ext_vector_type(8)));
typedef float  f32x4  __attribute__((ext_vector_type(4)));
typedef float  f32x16 __attribute__((ext_vector_type(16)));

union FragCast { int i[4]; bf16x8 v; };

__device__ __forceinline__ unsigned short f2bf(float f) {
    union { float f; unsigned int i; } x; x.f = f;
    unsigned int r = x.i + 0x7fffu + ((x.i >> 16) & 1u);
    return (unsigned short)(r >> 16);
}
// 4 VALU ops/pair round-half-up pack (R3; ties differ from RNE with P~2^-16).
__device__ __forceinline__ unsigned pkbf_fast(float a, float b) {  // lo16=a, hi16=b
    union { float f; unsigned u; } x, y; x.f = a; y.f = b;
    const unsigned ra = x.u + 0x8000u;
    const unsigned rb = y.u + 0x8000u;
    return (ra >> 16) | (rb & 0xffff0000u);
}
__device__ __forceinline__ void gl_lds16(const void* g, void* l) {
    __builtin_amdgcn_global_load_lds(
        (const __attribute__((address_space(1))) unsigned int*)g,
        (__attribute__((address_space(3))) unsigned int*)l, 16, 0, 0);
}

// ---------------------------------------------------------------------------
// Kernel W: wq fp32 [1536][512] -> wqb bf16 (contiguous convert)
// ---------------------------------------------------------------------------
__global__ __launch_bounds__(256) void k_prep_w(
        const float* __restrict__ wq, unsigned short* __restrict__ wqb) {
    const int idx = (blockIdx.x * 256 + threadIdx.x) * 4;
    float4 f = *(const float4*)(wq + idx);
    ushort4 u;
    u.x = f2bf(f.x); u.y = f2bf(f.y); u.z = f2bf(f.z); u.w = f2bf(f.w);
    *(ushort4*)(wqb + idx) = u;
}

// ---------------------------------------------------------------------------
// Kernel A: x fp32 [b][c][n] -> xt bf16 [b][n][c]  (64x64 LDS-tiled transpose)
// HBM-bound at ~27 us (128 MB read + 32 MB write): already at roofline.
// ---------------------------------------------------------------------------
__global__ __launch_bounds__(256) void k_transpose(
        const float* __restrict__ x, unsigned short* __restrict__ xt) {
    __shared__ unsigned short tile[64][68];
    const int t = threadIdx.x;
    const int lane4 = t & 15, grp = t >> 4;
    const int n0 = blockIdx.x * 64, c0 = blockIdx.y * 64, b = blockIdx.z;
    const size_t xb = (size_t)b * DIM * NPIX;
#pragma unroll
    for (int i = 0; i < 4; ++i) {
        int c = c0 + grp + i * 16;
        float4 f = *(const float4*)(x + xb + (size_t)c * NPIX + n0 + lane4 * 4);
        ushort4 u;
        u.x = f2bf(f.x); u.y = f2bf(f.y); u.z = f2bf(f.z); u.w = f2bf(f.w);
        *(ushort4*)&tile[grp + i * 16][lane4 * 4] = u;
    }
    __syncthreads();
    const size_t xtb = (size_t)b * NPIX * DIM;
#pragma unroll
    for (int i = 0; i < 4; ++i) {
        int nr = grp + i * 16;
        ushort4 v;
        v.x = tile[lane4 * 4 + 0][nr];
        v.y = tile[lane4 * 4 + 1][nr];
        v.z = tile[lane4 * 4 + 2][nr];
        v.w = tile[lane4 * 4 + 3][nr];
        *(ushort4*)(xt + xtb + (size_t)(n0 + nr) * DIM + c0 + lane4 * 4) = v;
    }
}

// ---------------------------------------------------------------------------
// Kernel B: QKV GEMM. R6 (verified): m97 single-buffer 2-barrier K-loop,
// 34816B LDS pool -> 4 blocks/CU. R5 (verified): coalesced LDS-transpose
// epilogue (WRITE_SIZE 147->98MB).
// ---------------------------------------------------------------------------
__global__ __launch_bounds__(256, 4) void k_qkv(
        const unsigned short* __restrict__ xt, const unsigned short* __restrict__ wqb,
        const float* __restrict__ bias,
        const float* __restrict__ hrel, const float* __restrict__ wrel,
        unsigned short* __restrict__ qs, unsigned short* __restrict__ ks,
        unsigned short* __restrict__ vt) {
    // 34816B pool: K-loop = At[8192] | Bt[8192] ushorts; epilogue = S[128][136]
    __shared__ unsigned short lds_pool[17408];
    unsigned short* At0 = lds_pool;            // 16 KB
    unsigned short* Bt0 = lds_pool + 8192;     // 16 KB
    const int t = threadIdx.x;
    const int lane = t & 63, w = t >> 6;
    const int r16 = lane & 15, q4 = lane >> 4;
    // XCD decode: gid&7 = XCD; per XCD, y (o-tile) innermost over 32 (x,b)
    const int gid = blockIdx.x;
    const int u = gid >> 3;
    const int y = u % 12;
    const int xz = (gid & 7) * 32 + u / 12;
    const int n0 = (xz & 7) * 128, o0 = y * 128, b = xz >> 3;
    const int wm = (w & 1) * 64, wn = (w >> 1) * 64;

    f32x4 acc[4][4];
#pragma unroll
    for (int i = 0; i < 4; ++i)
#pragma unroll
        for (int j = 0; j < 4; ++j) acc[i][j] = (f32x4){0.f, 0.f, 0.f, 0.f};

    const unsigned short* xtb = xt + (size_t)(b * NPIX + n0) * DIM;
    const int arow = t >> 3;
    const int aoff = (((t & 7) ^ (arow & 7)) * 16);
    const int fswz = (q4 ^ (r16 & 7)) << 3;

    for (int kk = 0; kk < 8; ++kk) {
        if (kk) __syncthreads();          // all waves done reading the buffer
        const int c1 = kk * 64;
#pragma unroll
        for (int j = 0; j < 4; ++j) {
            int r = j * 32 + arow;
            gl_lds16((const char*)(xtb + (size_t)r * DIM + c1) + aoff,
                     (char*)At0 + j * 4096 + w * 1024);
            gl_lds16((const char*)(wqb + (size_t)(o0 + r) * DIM + c1) + aoff,
                     (char*)Bt0 + j * 4096 + w * 1024);
        }
        asm volatile("s_waitcnt vmcnt(0)" ::: "memory");
        __syncthreads();
#pragma unroll
        for (int ksx = 0; ksx < 2; ++ksx) {
            const int fo = fswz ^ (ksx << 5);
            bf16x8 af[4], bfr[4];
#pragma unroll
            for (int mt = 0; mt < 4; ++mt)
                af[mt] = *reinterpret_cast<const bf16x8*>(
                    &At0[(wm + mt * 16 + r16) * 64 + fo]);
#pragma unroll
            for (int nt = 0; nt < 4; ++nt)
                bfr[nt] = *reinterpret_cast<const bf16x8*>(
                    &Bt0[(wn + nt * 16 + r16) * 64 + fo]);
#pragma unroll
            for (int mt = 0; mt < 4; ++mt)
#pragma unroll
                for (int nt = 0; nt < 4; ++nt)
                    acc[mt][nt] = __builtin_amdgcn_mfma_f32_16x16x32_bf16(
                        af[mt], bfr[nt], acc[mt][nt], 0, 0, 0);
        }
    }

    // ---- epilogue phase 1: acc -> LDS tile (math identical to before) ----
    __syncthreads();   // all waves done reading At/Bt before S overwrites
    const int sel = o0 >> 9;
    const int p0 = (o0 >> 6) & 7;
    if (sel == 2) {
        // S[o][n]: packed b64 writes (reg pairs are n-consecutive)
#pragma unroll
        for (int nt = 0; nt < 4; ++nt) {
            const int o_l = wn + nt * 16 + r16;
            const float bs = bias[o0 + o_l];
#pragma unroll
            for (int mt = 0; mt < 4; ++mt) {
                int2 wpair;
                wpair.x = (int)pkbf_fast(acc[mt][nt][0] + bs, acc[mt][nt][1] + bs);
                wpair.y = (int)pkbf_fast(acc[mt][nt][2] + bs, acc[mt][nt][3] + bs);
                *(int2*)&lds_pool[o_l * 136 + wm + mt * 16 + q4 * 4] = wpair;
            }
        }
    } else {
        // S[n][o]: scalar b16 writes (~2-way conflicts with 136 stride)
#pragma unroll
        for (int nt = 0; nt < 4; ++nt) {
            const int o = o0 + wn + nt * 16 + r16;
            const int o_l = o & 127;
            const float bs = bias[o];
            const int rem = o & 511;
#pragma unroll
            for (int mt = 0; mt < 4; ++mt) {
#pragma unroll
                for (int reg = 0; reg < 4; ++reg) {
                    const int n = n0 + wm + mt * 16 + q4 * 4 + reg;
                    float val = acc[mt][nt][reg] + bs;
                    if (sel == 0) {   // q: fold SCALE * log2(e) for exp2 softmax
                        val *= 0.1803368801111244f;
                    } else {
                        val += hrel[(n >> 5) * DIM + rem] + wrel[(n & 31) * DIM + rem];
                    }
                    lds_pool[(wm + mt * 16 + q4 * 4 + reg) * 136 + o_l] = f2bf(val);
                }
            }
        }
    }
    __syncthreads();

    // ---- epilogue phase 2: coalesced copy-out --------------------------
    const int pp = t >> 7, idx = t & 127;
    if (sel == 2) {
        // vt [bp][d][n]: 16B stores, 256B contiguous per (head,d) row
        unsigned short* vb = vt + ((size_t)(b * HEADS + p0 + pp) * HD) * NPIX + n0;
#pragma unroll
        for (int i = 0; i < 8; ++i) {
            const int f = i * 128 + idx;
            const int d = f >> 4, nc = f & 15;
            int4 v4 = *(const int4*)&lds_pool[(pp * 64 + d) * 136 + nc * 8];
            *(int4*)(vb + (size_t)d * NPIX + nc * 8) = v4;
        }
    } else {
        // qs/ks [bp][n][d]: 16B stores, 1KB contiguous per wave
        unsigned short* dst = (sel == 0 ? qs : ks) +
            ((size_t)(b * HEADS + p0 + pp) * NPIX + n0) * HD;
#pragma unroll
        for (int i = 0; i < 8; ++i) {
            const int f = i * 128 + idx;
            const int n = f >> 3, d8 = (f & 7) * 8;
            int4 v4 = *(const int4*)&lds_pool[n * 136 + pp * 64 + d8];
            *(int4*)(dst + (size_t)n * HD + d8) = v4;
        }
    }
}

// ---------------------------------------------------------------------------
// Kernel C: attention, 32x32x16 MFMA. K rows staged with the sigma-permutation
// so each lane's packed exp2 registers ARE the PV A-fragment -- zero shuffles.
// R8: K double-buffer dropped (m99-variant again, same as R6's qkv fix).
// Single Kt 16KB + Vt 16KB = 32KB -> 5 blocks/CU (was 48KB/3, measured 26.6%).
// Per-kt: barrier -> issue K then V loads -> vmcnt(4) (= the 4 oldest, i.e.
// K) + barrier -> S/exp2/pack -> vmcnt(0) + barrier -> PV. V latency hides
// under the ~1300cyc S phase as before; K's exposed L2 latency is covered by
// cross-block overlap (5 resident blocks vs 2).
// ---------------------------------------------------------------------------
__global__ __launch_bounds__(256, 5) void k_attn(
        const unsigned short* __restrict__ qs, const unsigned short* __restrict__ ks,
        const unsigned short* __restrict__ vt, float* __restrict__ out) {
    __shared__ unsigned short Kt[128 * 64];        // 16 KB [key][d], sigma+granule swizzle
    __shared__ unsigned short Vt[64 * 128];        // 16 KB [d][key], granule swizzle
    const int t = threadIdx.x;
    const int lane = t & 63, w = t >> 6;
    const int lc = lane & 31, h = lane >> 5;
    // XCD-aware decode: same (b,p) for 8 consecutive blocks on one XCD
    const int gid = blockIdx.x;
    const int g = gid >> 3;
    const int bp_ = (gid & 7) * 32 + (g >> 3);
    const int qt = g & 7;
    const size_t bp = (size_t)bp_;
    const int b = bp_ >> 3, p = bp_ & 7;
    const unsigned short* kbase = ks + bp * NPIX * HD;
    const unsigned short* vbase = vt + bp * HD * NPIX;

    // staging addresses (global side carries sigma + granule swizzle)
    const int krow = t >> 3;
    const int ksig = (((krow >> 2) ^ (krow >> 3)) & 1) ? 12 : 0;
    const int skrow = krow ^ ksig;                       // sigma source row
    const int koff = (((t & 7) ^ (krow & 7)) * 16);
    const int vrow = t >> 4;
    const int voff = (((t & 15) ^ (vrow & 7)) * 16);
    const int lsw = lc & 7;                              // read-side swizzle key

    // Q fragments direct from global: B[n=qrow=w*32+lc][k=h*8+j] per d-chunk
    const unsigned short* qrp = qs + (bp * NPIX + qt * 128 + w * 32 + lc) * HD;
    bf16x8 qf[4];
#pragma unroll
    for (int dk = 0; dk < 4; ++dk)
        qf[dk] = *reinterpret_cast<const bf16x8*>(qrp + dk * 16 + h * 8);

    // ones B-fragment for the denominator MFMA (bf16 1.0 = 0x3f80)
    FragCast ones;
    ones.i[0] = 0x3f803f80; ones.i[1] = 0x3f803f80;
    ones.i[2] = 0x3f803f80; ones.i[3] = 0x3f803f80;

    f32x16 oacc[2];
    oacc[0] = (f32x16)(0.f);
    oacc[1] = (f32x16)(0.f);
    f32x16 lacc = (f32x16)(0.f);

    for (int kt = 0; kt < 8; ++kt) {
        if (kt) __syncthreads();   // all waves done reading Kt/Vt of prev iter
        // stage K(kt) -- issued first (oldest in vmcnt FIFO)
#pragma unroll
        for (int j = 0; j < 4; ++j)
            gl_lds16((const char*)kbase + kt * 16384 + (skrow + j * 32) * 128 + koff,
                     (char*)Kt + j * 4096 + w * 1024);
        // stage V(kt)
#pragma unroll
        for (int j = 0; j < 4; ++j)
            gl_lds16((const char*)vbase + (vrow + j * 16) * 2048 + kt * 256 + voff,
                     (char*)Vt + j * 4096 + w * 1024);
        asm volatile("s_waitcnt vmcnt(4)" ::: "memory");   // K landed; V in flight
        __syncthreads();

        // ---- S^T = K'.Q^T per 32-key tile, exp2, pack ---------------------
        unsigned pk[4][8];
#pragma unroll
        for (int T = 0; T < 4; ++T) {
            f32x16 s = (f32x16)(0.f);
            const int krb = (T * 32 + lc) * 64;
#pragma unroll
            for (int dk = 0; dk < 4; ++dk) {
                bf16x8 ak = *reinterpret_cast<const bf16x8*>(
                    &Kt[krb + (((dk * 2 + h) ^ lsw) * 8)]);
                s = __builtin_amdgcn_mfma_f32_32x32x16_bf16(ak, qf[dk], s, 0, 0, 0);
            }
            float e[16];
#pragma unroll
            for (int r = 0; r < 16; ++r) e[r] = __builtin_amdgcn_exp2f(s[r]);
#pragma unroll
            for (int j = 0; j < 8; ++j) pk[T][j] = pkbf_fast(e[2 * j], e[2 * j + 1]);
        }

        // own V loads done; all waves' V visible after barrier
        asm volatile("s_waitcnt vmcnt(0)" ::: "memory");
        __syncthreads();

        // ---- PV: A-frag = lane's own pk registers (sigma made it so) ------
        // lacc accumulates P * ones == per-q-row softmax denominator, in the
        // exact same D-register layout as oacc.
#pragma unroll
        for (int c = 0; c < 8; ++c) {
            FragCast fa;
            fa.i[0] = (int)pk[c >> 1][(c & 1) * 4 + 0];
            fa.i[1] = (int)pk[c >> 1][(c & 1) * 4 + 1];
            fa.i[2] = (int)pk[c >> 1][(c & 1) * 4 + 2];
            fa.i[3] = (int)pk[c >> 1][(c & 1) * 4 + 3];
            const int gv = ((c * 2 + h) ^ lsw) * 8;
#pragma unroll
            for (int nt = 0; nt < 2; ++nt) {
                bf16x8 bv = *reinterpret_cast<const bf16x8*>(
                    &Vt[(nt * 32 + lc) * 128 + gv]);
                oacc[nt] = __builtin_amdgcn_mfma_f32_32x32x16_bf16(
                    fa.v, bv, oacc[nt], 0, 0, 0);
            }
            lacc = __builtin_amdgcn_mfma_f32_32x32x16_bf16(fa.v, ones.v, lacc, 0, 0, 0);
        }
    }

    // ---- normalize + store: linv comes straight from lacc (row-aligned) ---
#pragma unroll
    for (int nt = 0; nt < 2; ++nt) {
        const int d = nt * 32 + lc;
        float* ob = out + ((size_t)(b * DIM + p * HD + d)) * NPIX + qt * 128 + w * 32;
#pragma unroll
        for (int gg = 0; gg < 4; ++gg) {
            float4 o4;
            o4.x = oacc[nt][4 * gg + 0] * __builtin_amdgcn_rcpf(lacc[4 * gg + 0]);
            o4.y = oacc[nt][4 * gg + 1] * __builtin_amdgcn_rcpf(lacc[4 * gg + 1]);
            o4.z = oacc[nt][4 * gg + 2] * __builtin_amdgcn_rcpf(lacc[4 * gg + 2]);
            o4.w = oacc[nt][4 * gg + 3] * __builtin_amdgcn_rcpf(lacc[4 * gg + 3]);
            *(float4*)(ob + 8 * gg + 4 * h) = o4;
        }
    }
}

// ---------------------------------------------------------------------------
extern "C" void kernel_launch(void* const* d_in, const int* in_sizes, int n_in,
                              void* d_out, int out_size, void* d_ws, size_t ws_size,
                              hipStream_t stream) {
    const float* x    = (const float*)d_in[0];
    const float* wq   = (const float*)d_in[1];
    const float* bias = (const float*)d_in[2];
    const float* hrel = (const float*)d_in[3];
    const float* wrel = (const float*)d_in[4];
    float* out = (float*)d_out;

    char* ws = (char*)d_ws;
    unsigned short* qs  = (unsigned short*)(ws);                 // 32 MB [b][p][n][d]
    unsigned short* ks  = (unsigned short*)(ws + 33554432u);     // 32 MB [b][p][n][d]
    unsigned short* vt  = (unsigned short*)(ws + 67108864u);     // 32 MB [b][p][d][n]
    unsigned short* xt  = (unsigned short*)d_out;                // 32 MB [b][n][c]
    unsigned short* wqb = (unsigned short*)((char*)d_out + 33554432u);  // 1.5 MB

    k_prep_w<<<dim3(768), 256, 0, stream>>>(wq, wqb);
    k_transpose<<<dim3(16, 8, 32), 256, 0, stream>>>(x, xt);
    k_qkv<<<dim3(3072), 256, 0, stream>>>(xt, wqb, bias, hrel, wrel, qs, ks, vt);
    k_attn<<<dim3(2048), 256, 0, stream>>>(qs, ks, vt, out);
}

// Round 9
// 323.661 us; speedup vs baseline: 2.7187x; 2.7187x over previous
//
#include <hip/hip_runtime.h>
#include <hip/hip_bf16.h>

// Problem constants
#define NB    32
#define DIM   512
#define HEADS 8
#define HD    64
#define NPIX  1024   // H*W = 32*32

typedef __bf16 bf16x8 __attribute__((ext_vector_type(8)));
typedef float  f32x4  __attribute__((ext_vector_type(4)));
typedef float  f32x16 __attribute__((ext_vector_type(16)));

union FragCast { int i[4]; bf16x8 v; };

__device__ __forceinline__ unsigned short f2bf(float f) {
    union { float f; unsigned int i; } x; x.f = f;
    unsigned int r = x.i + 0x7fffu + ((x.i >> 16) & 1u);
    return (unsigned short)(r >> 16);
}
// 4 VALU ops/pair round-half-up pack (R3; ties differ from RNE with P~2^-16).
__device__ __forceinline__ unsigned pkbf_fast(float a, float b) {  // lo16=a, hi16=b
    union { float f; unsigned u; } x, y; x.f = a; y.f = b;
    const unsigned ra = x.u + 0x8000u;
    const unsigned rb = y.u + 0x8000u;
    return (ra >> 16) | (rb & 0xffff0000u);
}
__device__ __forceinline__ void gl_lds16(const void* g, void* l) {
    __builtin_amdgcn_global_load_lds(
        (const __attribute__((address_space(1))) unsigned int*)g,
        (__attribute__((address_space(3))) unsigned int*)l, 16, 0, 0);
}

// ---------------------------------------------------------------------------
// Kernel W: wq fp32 [1536][512] -> wqb bf16 (contiguous convert)
// ---------------------------------------------------------------------------
__global__ __launch_bounds__(256) void k_prep_w(
        const float* __restrict__ wq, unsigned short* __restrict__ wqb) {
    const int idx = (blockIdx.x * 256 + threadIdx.x) * 4;
    float4 f = *(const float4*)(wq + idx);
    ushort4 u;
    u.x = f2bf(f.x); u.y = f2bf(f.y); u.z = f2bf(f.z); u.w = f2bf(f.w);
    *(ushort4*)(wqb + idx) = u;
}

// ---------------------------------------------------------------------------
// Kernel A: x fp32 [b][c][n] -> xt bf16 [b][n][c]  (64x64 LDS-tiled transpose)
// HBM-bound at ~27 us (128 MB read + 32 MB write): already at roofline.
// ---------------------------------------------------------------------------
__global__ __launch_bounds__(256) void k_transpose(
        const float* __restrict__ x, unsigned short* __restrict__ xt) {
    __shared__ unsigned short tile[64][68];
    const int t = threadIdx.x;
    const int lane4 = t & 15, grp = t >> 4;
    const int n0 = blockIdx.x * 64, c0 = blockIdx.y * 64, b = blockIdx.z;
    const size_t xb = (size_t)b * DIM * NPIX;
#pragma unroll
    for (int i = 0; i < 4; ++i) {
        int c = c0 + grp + i * 16;
        float4 f = *(const float4*)(x + xb + (size_t)c * NPIX + n0 + lane4 * 4);
        ushort4 u;
        u.x = f2bf(f.x); u.y = f2bf(f.y); u.z = f2bf(f.z); u.w = f2bf(f.w);
        *(ushort4*)&tile[grp + i * 16][lane4 * 4] = u;
    }
    __syncthreads();
    const size_t xtb = (size_t)b * NPIX * DIM;
#pragma unroll
    for (int i = 0; i < 4; ++i) {
        int nr = grp + i * 16;
        ushort4 v;
        v.x = tile[lane4 * 4 + 0][nr];
        v.y = tile[lane4 * 4 + 1][nr];
        v.z = tile[lane4 * 4 + 2][nr];
        v.w = tile[lane4 * 4 + 3][nr];
        *(ushort4*)(xt + xtb + (size_t)(n0 + nr) * DIM + c0 + lane4 * 4) = v;
    }
}

// ---------------------------------------------------------------------------
// Kernel B: QKV GEMM. R6 (verified): m97 single-buffer 2-barrier K-loop,
// 34816B LDS pool -> 4 blocks/CU. R5 (verified): coalesced LDS-transpose
// epilogue (WRITE_SIZE 147->98MB).
// ---------------------------------------------------------------------------
__global__ __launch_bounds__(256, 4) void k_qkv(
        const unsigned short* __restrict__ xt, const unsigned short* __restrict__ wqb,
        const float* __restrict__ bias,
        const float* __restrict__ hrel, const float* __restrict__ wrel,
        unsigned short* __restrict__ qs, unsigned short* __restrict__ ks,
        unsigned short* __restrict__ vt) {
    // 34816B pool: K-loop = At[8192] | Bt[8192] ushorts; epilogue = S[128][136]
    __shared__ unsigned short lds_pool[17408];
    unsigned short* At0 = lds_pool;            // 16 KB
    unsigned short* Bt0 = lds_pool + 8192;     // 16 KB
    const int t = threadIdx.x;
    const int lane = t & 63, w = t >> 6;
    const int r16 = lane & 15, q4 = lane >> 4;
    // XCD decode: gid&7 = XCD; per XCD, y (o-tile) innermost over 32 (x,b)
    const int gid = blockIdx.x;
    const int u = gid >> 3;
    const int y = u % 12;
    const int xz = (gid & 7) * 32 + u / 12;
    const int n0 = (xz & 7) * 128, o0 = y * 128, b = xz >> 3;
    const int wm = (w & 1) * 64, wn = (w >> 1) * 64;

    f32x4 acc[4][4];
#pragma unroll
    for (int i = 0; i < 4; ++i)
#pragma unroll
        for (int j = 0; j < 4; ++j) acc[i][j] = (f32x4){0.f, 0.f, 0.f, 0.f};

    const unsigned short* xtb = xt + (size_t)(b * NPIX + n0) * DIM;
    const int arow = t >> 3;
    const int aoff = (((t & 7) ^ (arow & 7)) * 16);
    const int fswz = (q4 ^ (r16 & 7)) << 3;

    for (int kk = 0; kk < 8; ++kk) {
        if (kk) __syncthreads();          // all waves done reading the buffer
        const int c1 = kk * 64;
#pragma unroll
        for (int j = 0; j < 4; ++j) {
            int r = j * 32 + arow;
            gl_lds16((const char*)(xtb + (size_t)r * DIM + c1) + aoff,
                     (char*)At0 + j * 4096 + w * 1024);
            gl_lds16((const char*)(wqb + (size_t)(o0 + r) * DIM + c1) + aoff,
                     (char*)Bt0 + j * 4096 + w * 1024);
        }
        asm volatile("s_waitcnt vmcnt(0)" ::: "memory");
        __syncthreads();
#pragma unroll
        for (int ksx = 0; ksx < 2; ++ksx) {
            const int fo = fswz ^ (ksx << 5);
            bf16x8 af[4], bfr[4];
#pragma unroll
            for (int mt = 0; mt < 4; ++mt)
                af[mt] = *reinterpret_cast<const bf16x8*>(
                    &At0[(wm + mt * 16 + r16) * 64 + fo]);
#pragma unroll
            for (int nt = 0; nt < 4; ++nt)
                bfr[nt] = *reinterpret_cast<const bf16x8*>(
                    &Bt0[(wn + nt * 16 + r16) * 64 + fo]);
#pragma unroll
            for (int mt = 0; mt < 4; ++mt)
#pragma unroll
                for (int nt = 0; nt < 4; ++nt)
                    acc[mt][nt] = __builtin_amdgcn_mfma_f32_16x16x32_bf16(
                        af[mt], bfr[nt], acc[mt][nt], 0, 0, 0);
        }
    }

    // ---- epilogue phase 1: acc -> LDS tile (math identical to before) ----
    __syncthreads();   // all waves done reading At/Bt before S overwrites
    const int sel = o0 >> 9;
    const int p0 = (o0 >> 6) & 7;
    if (sel == 2) {
        // S[o][n]: packed b64 writes (reg pairs are n-consecutive)
#pragma unroll
        for (int nt = 0; nt < 4; ++nt) {
            const int o_l = wn + nt * 16 + r16;
            const float bs = bias[o0 + o_l];
#pragma unroll
            for (int mt = 0; mt < 4; ++mt) {
                int2 wpair;
                wpair.x = (int)pkbf_fast(acc[mt][nt][0] + bs, acc[mt][nt][1] + bs);
                wpair.y = (int)pkbf_fast(acc[mt][nt][2] + bs, acc[mt][nt][3] + bs);
                *(int2*)&lds_pool[o_l * 136 + wm + mt * 16 + q4 * 4] = wpair;
            }
        }
    } else {
        // S[n][o]: scalar b16 writes (~2-way conflicts with 136 stride)
#pragma unroll
        for (int nt = 0; nt < 4; ++nt) {
            const int o = o0 + wn + nt * 16 + r16;
            const int o_l = o & 127;
            const float bs = bias[o];
            const int rem = o & 511;
#pragma unroll
            for (int mt = 0; mt < 4; ++mt) {
#pragma unroll
                for (int reg = 0; reg < 4; ++reg) {
                    const int n = n0 + wm + mt * 16 + q4 * 4 + reg;
                    float val = acc[mt][nt][reg] + bs;
                    if (sel == 0) {   // q: fold SCALE * log2(e) for exp2 softmax
                        val *= 0.1803368801111244f;
                    } else {
                        val += hrel[(n >> 5) * DIM + rem] + wrel[(n & 31) * DIM + rem];
                    }
                    lds_pool[(wm + mt * 16 + q4 * 4 + reg) * 136 + o_l] = f2bf(val);
                }
            }
        }
    }
    __syncthreads();

    // ---- epilogue phase 2: coalesced copy-out --------------------------
    const int pp = t >> 7, idx = t & 127;
    if (sel == 2) {
        // vt [bp][d][n]: 16B stores, 256B contiguous per (head,d) row
        unsigned short* vb = vt + ((size_t)(b * HEADS + p0 + pp) * HD) * NPIX + n0;
#pragma unroll
        for (int i = 0; i < 8; ++i) {
            const int f = i * 128 + idx;
            const int d = f >> 4, nc = f & 15;
            int4 v4 = *(const int4*)&lds_pool[(pp * 64 + d) * 136 + nc * 8];
            *(int4*)(vb + (size_t)d * NPIX + nc * 8) = v4;
        }
    } else {
        // qs/ks [bp][n][d]: 16B stores, 1KB contiguous per wave
        unsigned short* dst = (sel == 0 ? qs : ks) +
            ((size_t)(b * HEADS + p0 + pp) * NPIX + n0) * HD;
#pragma unroll
        for (int i = 0; i < 8; ++i) {
            const int f = i * 128 + idx;
            const int n = f >> 3, d8 = (f & 7) * 8;
            int4 v4 = *(const int4*)&lds_pool[n * 136 + pp * 64 + d8];
            *(int4*)(dst + (size_t)n * HD + d8) = v4;
        }
    }
}

// ---------------------------------------------------------------------------
// Kernel C: attention, 32x32x16 MFMA, sigma-permuted K staging (packed exp2
// regs ARE the PV A-fragment). R9: R8's single-buffer structure KEPT (Kt 16KB
// + Vt 16KB = 32KB LDS -> 5 blocks/CU LDS-limit) but launch_bounds fixed
// (256,5)->(256,4). R8's bound squeezed the allocator to 48 VGPR -> oacc/pk
// spilled to scratch (WRITE_SIZE 67MB->1.85GB, FETCH 50->990MB, 754us).
// (256,4) caps at 128 VGPR (kernel needs ~84, no spill); runtime occupancy
// is still LDS-limited at 5 blocks/CU since launch_bounds only constrains
// the allocator, not the scheduler.
// ---------------------------------------------------------------------------
__global__ __launch_bounds__(256, 4) void k_attn(
        const unsigned short* __restrict__ qs, const unsigned short* __restrict__ ks,
        const unsigned short* __restrict__ vt, float* __restrict__ out) {
    __shared__ unsigned short Kt[128 * 64];        // 16 KB [key][d], sigma+granule swizzle
    __shared__ unsigned short Vt[64 * 128];        // 16 KB [d][key], granule swizzle
    const int t = threadIdx.x;
    const int lane = t & 63, w = t >> 6;
    const int lc = lane & 31, h = lane >> 5;
    // XCD-aware decode: same (b,p) for 8 consecutive blocks on one XCD
    const int gid = blockIdx.x;
    const int g = gid >> 3;
    const int bp_ = (gid & 7) * 32 + (g >> 3);
    const int qt = g & 7;
    const size_t bp = (size_t)bp_;
    const int b = bp_ >> 3, p = bp_ & 7;
    const unsigned short* kbase = ks + bp * NPIX * HD;
    const unsigned short* vbase = vt + bp * HD * NPIX;

    // staging addresses (global side carries sigma + granule swizzle)
    const int krow = t >> 3;
    const int ksig = (((krow >> 2) ^ (krow >> 3)) & 1) ? 12 : 0;
    const int skrow = krow ^ ksig;                       // sigma source row
    const int koff = (((t & 7) ^ (krow & 7)) * 16);
    const int vrow = t >> 4;
    const int voff = (((t & 15) ^ (vrow & 7)) * 16);
    const int lsw = lc & 7;                              // read-side swizzle key

    // Q fragments direct from global: B[n=qrow=w*32+lc][k=h*8+j] per d-chunk
    const unsigned short* qrp = qs + (bp * NPIX + qt * 128 + w * 32 + lc) * HD;
    bf16x8 qf[4];
#pragma unroll
    for (int dk = 0; dk < 4; ++dk)
        qf[dk] = *reinterpret_cast<const bf16x8*>(qrp + dk * 16 + h * 8);

    // ones B-fragment for the denominator MFMA (bf16 1.0 = 0x3f80)
    FragCast ones;
    ones.i[0] = 0x3f803f80; ones.i[1] = 0x3f803f80;
    ones.i[2] = 0x3f803f80; ones.i[3] = 0x3f803f80;

    f32x16 oacc[2];
    oacc[0] = (f32x16)(0.f);
    oacc[1] = (f32x16)(0.f);
    f32x16 lacc = (f32x16)(0.f);

    for (int kt = 0; kt < 8; ++kt) {
        if (kt) __syncthreads();   // all waves done reading Kt/Vt of prev iter
        // stage K(kt) -- issued first (oldest in vmcnt FIFO)
#pragma unroll
        for (int j = 0; j < 4; ++j)
            gl_lds16((const char*)kbase + kt * 16384 + (skrow + j * 32) * 128 + koff,
                     (char*)Kt + j * 4096 + w * 1024);
        // stage V(kt)
#pragma unroll
        for (int j = 0; j < 4; ++j)
            gl_lds16((const char*)vbase + (vrow + j * 16) * 2048 + kt * 256 + voff,
                     (char*)Vt + j * 4096 + w * 1024);
        asm volatile("s_waitcnt vmcnt(4)" ::: "memory");   // K landed; V in flight
        __syncthreads();

        // ---- S^T = K'.Q^T per 32-key tile, exp2, pack ---------------------
        unsigned pk[4][8];
#pragma unroll
        for (int T = 0; T < 4; ++T) {
            f32x16 s = (f32x16)(0.f);
            const int krb = (T * 32 + lc) * 64;
#pragma unroll
            for (int dk = 0; dk < 4; ++dk) {
                bf16x8 ak = *reinterpret_cast<const bf16x8*>(
                    &Kt[krb + (((dk * 2 + h) ^ lsw) * 8)]);
                s = __builtin_amdgcn_mfma_f32_32x32x16_bf16(ak, qf[dk], s, 0, 0, 0);
            }
            float e[16];
#pragma unroll
            for (int r = 0; r < 16; ++r) e[r] = __builtin_amdgcn_exp2f(s[r]);
#pragma unroll
            for (int j = 0; j < 8; ++j) pk[T][j] = pkbf_fast(e[2 * j], e[2 * j + 1]);
        }

        // own V loads done; all waves' V visible after barrier
        asm volatile("s_waitcnt vmcnt(0)" ::: "memory");
        __syncthreads();

        // ---- PV: A-frag = lane's own pk registers (sigma made it so) ------
        // lacc accumulates P * ones == per-q-row softmax denominator, in the
        // exact same D-register layout as oacc.
#pragma unroll
        for (int c = 0; c < 8; ++c) {
            FragCast fa;
            fa.i[0] = (int)pk[c >> 1][(c & 1) * 4 + 0];
            fa.i[1] = (int)pk[c >> 1][(c & 1) * 4 + 1];
            fa.i[2] = (int)pk[c >> 1][(c & 1) * 4 + 2];
            fa.i[3] = (int)pk[c >> 1][(c & 1) * 4 + 3];
            const int gv = ((c * 2 + h) ^ lsw) * 8;
#pragma unroll
            for (int nt = 0; nt < 2; ++nt) {
                bf16x8 bv = *reinterpret_cast<const bf16x8*>(
                    &Vt[(nt * 32 + lc) * 128 + gv]);
                oacc[nt] = __builtin_amdgcn_mfma_f32_32x32x16_bf16(
                    fa.v, bv, oacc[nt], 0, 0, 0);
            }
            lacc = __builtin_amdgcn_mfma_f32_32x32x16_bf16(fa.v, ones.v, lacc, 0, 0, 0);
        }
    }

    // ---- normalize + store: linv comes straight from lacc (row-aligned) ---
#pragma unroll
    for (int nt = 0; nt < 2; ++nt) {
        const int d = nt * 32 + lc;
        float* ob = out + ((size_t)(b * DIM + p * HD + d)) * NPIX + qt * 128 + w * 32;
#pragma unroll
        for (int gg = 0; gg < 4; ++gg) {
            float4 o4;
            o4.x = oacc[nt][4 * gg + 0] * __builtin_amdgcn_rcpf(lacc[4 * gg + 0]);
            o4.y = oacc[nt][4 * gg + 1] * __builtin_amdgcn_rcpf(lacc[4 * gg + 1]);
            o4.z = oacc[nt][4 * gg + 2] * __builtin_amdgcn_rcpf(lacc[4 * gg + 2]);
            o4.w = oacc[nt][4 * gg + 3] * __builtin_amdgcn_rcpf(lacc[4 * gg + 3]);
            *(float4*)(ob + 8 * gg + 4 * h) = o4;
        }
    }
}

// ---------------------------------------------------------------------------
extern "C" void kernel_launch(void* const* d_in, const int* in_sizes, int n_in,
                              void* d_out, int out_size, void* d_ws, size_t ws_size,
                              hipStream_t stream) {
    const float* x    = (const float*)d_in[0];
    const float* wq   = (const float*)d_in[1];
    const float* bias = (const float*)d_in[2];
    const float* hrel = (const float*)d_in[3];
    const float* wrel = (const float*)d_in[4];
    float* out = (float*)d_out;

    char* ws = (char*)d_ws;
    unsigned short* qs  = (unsigned short*)(ws);                 // 32 MB [b][p][n][d]
    unsigned short* ks  = (unsigned short*)(ws + 33554432u);     // 32 MB [b][p][n][d]
    unsigned short* vt  = (unsigned short*)(ws + 67108864u);     // 32 MB [b][p][d][n]
    unsigned short* xt  = (unsigned short*)d_out;                // 32 MB [b][n][c]
    unsigned short* wqb = (unsigned short*)((char*)d_out + 33554432u);  // 1.5 MB

    k_prep_w<<<dim3(768), 256, 0, stream>>>(wq, wqb);
    k_transpose<<<dim3(16, 8, 32), 256, 0, stream>>>(x, xt);
    k_qkv<<<dim3(3072), 256, 0, stream>>>(xt, wqb, bias, hrel, wrel, qs, ks, vt);
    k_attn<<<dim3(2048), 256, 0, stream>>>(qs, ks, vt, out);
}

// Round 10
// 272.264 us; speedup vs baseline: 3.2319x; 1.1888x over previous
//
#include <hip/hip_runtime.h>
#include <hip/hip_bf16.h>

// Problem constants
#define NB    32
#define DIM   512
#define HEADS 8
#define HD    64
#define NPIX  1024   // H*W = 32*32

typedef __bf16 bf16x8 __attribute__((ext_vector_type(8)));
typedef float  f32x4  __attribute__((ext_vector_type(4)));
typedef float  f32x16 __attribute__((ext_vector_type(16)));

union FragCast { int i[4]; bf16x8 v; };

__device__ __forceinline__ unsigned short f2bf(float f) {
    union { float f; unsigned int i; } x; x.f = f;
    unsigned int r = x.i + 0x7fffu + ((x.i >> 16) & 1u);
    return (unsigned short)(r >> 16);
}
// 4 VALU ops/pair round-half-up pack (R3; ties differ from RNE with P~2^-16).
__device__ __forceinline__ unsigned pkbf_fast(float a, float b) {  // lo16=a, hi16=b
    union { float f; unsigned u; } x, y; x.f = a; y.f = b;
    const unsigned ra = x.u + 0x8000u;
    const unsigned rb = y.u + 0x8000u;
    return (ra >> 16) | (rb & 0xffff0000u);
}
__device__ __forceinline__ void gl_lds16(const void* g, void* l) {
    __builtin_amdgcn_global_load_lds(
        (const __attribute__((address_space(1))) unsigned int*)g,
        (__attribute__((address_space(3))) unsigned int*)l, 16, 0, 0);
}

// ---------------------------------------------------------------------------
// Kernel W: wq fp32 [1536][512] -> wqb bf16 (contiguous convert)
// ---------------------------------------------------------------------------
__global__ __launch_bounds__(256) void k_prep_w(
        const float* __restrict__ wq, unsigned short* __restrict__ wqb) {
    const int idx = (blockIdx.x * 256 + threadIdx.x) * 4;
    float4 f = *(const float4*)(wq + idx);
    ushort4 u;
    u.x = f2bf(f.x); u.y = f2bf(f.y); u.z = f2bf(f.z); u.w = f2bf(f.w);
    *(ushort4*)(wqb + idx) = u;
}

// ---------------------------------------------------------------------------
// Kernel A: x fp32 [b][c][n] -> xt bf16 [b][n][c]  (64x64 LDS-tiled transpose)
// HBM-bound at ~27 us (128 MB read + 32 MB write): already at roofline.
// ---------------------------------------------------------------------------
__global__ __launch_bounds__(256) void k_transpose(
        const float* __restrict__ x, unsigned short* __restrict__ xt) {
    __shared__ unsigned short tile[64][68];
    const int t = threadIdx.x;
    const int lane4 = t & 15, grp = t >> 4;
    const int n0 = blockIdx.x * 64, c0 = blockIdx.y * 64, b = blockIdx.z;
    const size_t xb = (size_t)b * DIM * NPIX;
#pragma unroll
    for (int i = 0; i < 4; ++i) {
        int c = c0 + grp + i * 16;
        float4 f = *(const float4*)(x + xb + (size_t)c * NPIX + n0 + lane4 * 4);
        ushort4 u;
        u.x = f2bf(f.x); u.y = f2bf(f.y); u.z = f2bf(f.z); u.w = f2bf(f.w);
        *(ushort4*)&tile[grp + i * 16][lane4 * 4] = u;
    }
    __syncthreads();
    const size_t xtb = (size_t)b * NPIX * DIM;
#pragma unroll
    for (int i = 0; i < 4; ++i) {
        int nr = grp + i * 16;
        ushort4 v;
        v.x = tile[lane4 * 4 + 0][nr];
        v.y = tile[lane4 * 4 + 1][nr];
        v.z = tile[lane4 * 4 + 2][nr];
        v.w = tile[lane4 * 4 + 3][nr];
        *(ushort4*)(xt + xtb + (size_t)(n0 + nr) * DIM + c0 + lane4 * 4) = v;
    }
}

// ---------------------------------------------------------------------------
// Kernel B: QKV GEMM. R6 (verified): m97 single-buffer 2-barrier K-loop,
// 34816B LDS pool -> 4 blocks/CU. R5 (verified): coalesced LDS-transpose
// epilogue (WRITE_SIZE 147->98MB).
// ---------------------------------------------------------------------------
__global__ __launch_bounds__(256, 4) void k_qkv(
        const unsigned short* __restrict__ xt, const unsigned short* __restrict__ wqb,
        const float* __restrict__ bias,
        const float* __restrict__ hrel, const float* __restrict__ wrel,
        unsigned short* __restrict__ qs, unsigned short* __restrict__ ks,
        unsigned short* __restrict__ vt) {
    // 34816B pool: K-loop = At[8192] | Bt[8192] ushorts; epilogue = S[128][136]
    __shared__ unsigned short lds_pool[17408];
    unsigned short* At0 = lds_pool;            // 16 KB
    unsigned short* Bt0 = lds_pool + 8192;     // 16 KB
    const int t = threadIdx.x;
    const int lane = t & 63, w = t >> 6;
    const int r16 = lane & 15, q4 = lane >> 4;
    // XCD decode: gid&7 = XCD; per XCD, y (o-tile) innermost over 32 (x,b)
    const int gid = blockIdx.x;
    const int u = gid >> 3;
    const int y = u % 12;
    const int xz = (gid & 7) * 32 + u / 12;
    const int n0 = (xz & 7) * 128, o0 = y * 128, b = xz >> 3;
    const int wm = (w & 1) * 64, wn = (w >> 1) * 64;

    f32x4 acc[4][4];
#pragma unroll
    for (int i = 0; i < 4; ++i)
#pragma unroll
        for (int j = 0; j < 4; ++j) acc[i][j] = (f32x4){0.f, 0.f, 0.f, 0.f};

    const unsigned short* xtb = xt + (size_t)(b * NPIX + n0) * DIM;
    const int arow = t >> 3;
    const int aoff = (((t & 7) ^ (arow & 7)) * 16);
    const int fswz = (q4 ^ (r16 & 7)) << 3;

    for (int kk = 0; kk < 8; ++kk) {
        if (kk) __syncthreads();          // all waves done reading the buffer
        const int c1 = kk * 64;
#pragma unroll
        for (int j = 0; j < 4; ++j) {
            int r = j * 32 + arow;
            gl_lds16((const char*)(xtb + (size_t)r * DIM + c1) + aoff,
                     (char*)At0 + j * 4096 + w * 1024);
            gl_lds16((const char*)(wqb + (size_t)(o0 + r) * DIM + c1) + aoff,
                     (char*)Bt0 + j * 4096 + w * 1024);
        }
        asm volatile("s_waitcnt vmcnt(0)" ::: "memory");
        __syncthreads();
#pragma unroll
        for (int ksx = 0; ksx < 2; ++ksx) {
            const int fo = fswz ^ (ksx << 5);
            bf16x8 af[4], bfr[4];
#pragma unroll
            for (int mt = 0; mt < 4; ++mt)
                af[mt] = *reinterpret_cast<const bf16x8*>(
                    &At0[(wm + mt * 16 + r16) * 64 + fo]);
#pragma unroll
            for (int nt = 0; nt < 4; ++nt)
                bfr[nt] = *reinterpret_cast<const bf16x8*>(
                    &Bt0[(wn + nt * 16 + r16) * 64 + fo]);
#pragma unroll
            for (int mt = 0; mt < 4; ++mt)
#pragma unroll
                for (int nt = 0; nt < 4; ++nt)
                    acc[mt][nt] = __builtin_amdgcn_mfma_f32_16x16x32_bf16(
                        af[mt], bfr[nt], acc[mt][nt], 0, 0, 0);
        }
    }

    // ---- epilogue phase 1: acc -> LDS tile (math identical to before) ----
    __syncthreads();   // all waves done reading At/Bt before S overwrites
    const int sel = o0 >> 9;
    const int p0 = (o0 >> 6) & 7;
    if (sel == 2) {
        // S[o][n]: packed b64 writes (reg pairs are n-consecutive)
#pragma unroll
        for (int nt = 0; nt < 4; ++nt) {
            const int o_l = wn + nt * 16 + r16;
            const float bs = bias[o0 + o_l];
#pragma unroll
            for (int mt = 0; mt < 4; ++mt) {
                int2 wpair;
                wpair.x = (int)pkbf_fast(acc[mt][nt][0] + bs, acc[mt][nt][1] + bs);
                wpair.y = (int)pkbf_fast(acc[mt][nt][2] + bs, acc[mt][nt][3] + bs);
                *(int2*)&lds_pool[o_l * 136 + wm + mt * 16 + q4 * 4] = wpair;
            }
        }
    } else {
        // S[n][o]: scalar b16 writes (~2-way conflicts with 136 stride)
#pragma unroll
        for (int nt = 0; nt < 4; ++nt) {
            const int o = o0 + wn + nt * 16 + r16;
            const int o_l = o & 127;
            const float bs = bias[o];
            const int rem = o & 511;
#pragma unroll
            for (int mt = 0; mt < 4; ++mt) {
#pragma unroll
                for (int reg = 0; reg < 4; ++reg) {
                    const int n = n0 + wm + mt * 16 + q4 * 4 + reg;
                    float val = acc[mt][nt][reg] + bs;
                    if (sel == 0) {   // q: fold SCALE * log2(e) for exp2 softmax
                        val *= 0.1803368801111244f;
                    } else {
                        val += hrel[(n >> 5) * DIM + rem] + wrel[(n & 31) * DIM + rem];
                    }
                    lds_pool[(wm + mt * 16 + q4 * 4 + reg) * 136 + o_l] = f2bf(val);
                }
            }
        }
    }
    __syncthreads();

    // ---- epilogue phase 2: coalesced copy-out --------------------------
    const int pp = t >> 7, idx = t & 127;
    if (sel == 2) {
        // vt [bp][d][n]: 16B stores, 256B contiguous per (head,d) row
        unsigned short* vb = vt + ((size_t)(b * HEADS + p0 + pp) * HD) * NPIX + n0;
#pragma unroll
        for (int i = 0; i < 8; ++i) {
            const int f = i * 128 + idx;
            const int d = f >> 4, nc = f & 15;
            int4 v4 = *(const int4*)&lds_pool[(pp * 64 + d) * 136 + nc * 8];
            *(int4*)(vb + (size_t)d * NPIX + nc * 8) = v4;
        }
    } else {
        // qs/ks [bp][n][d]: 16B stores, 1KB contiguous per wave
        unsigned short* dst = (sel == 0 ? qs : ks) +
            ((size_t)(b * HEADS + p0 + pp) * NPIX + n0) * HD;
#pragma unroll
        for (int i = 0; i < 8; ++i) {
            const int f = i * 128 + idx;
            const int n = f >> 3, d8 = (f & 7) * 8;
            int4 v4 = *(const int4*)&lds_pool[n * 136 + pp * 64 + d8];
            *(int4*)(dst + (size_t)n * HD + d8) = v4;
        }
    }
}

// ---------------------------------------------------------------------------
// Kernel C: attention, 32x32x16 MFMA, sigma-permuted K staging (packed exp2
// regs ARE the PV A-fragment). R10: REVERTED to the verified R7 structure
// (Kt dbuf 32KB + Vt 16KB = 48KB, bound (256,3), ~84+80 unified regs, no
// spill). R8/R9 established this kernel CANNOT fit 4 waves/EU: unified
// VGPR+AGPR footprint ~164 > 128 cap -> spills (R9: VGPR 64, WRITE 170MB).
// 3 blocks/CU is the occupancy ceiling at this register footprint.
// NEW (T5): s_setprio(1) around MFMA clusters -- 3 independent blocks/CU sit
// at different phases (S-MFMA vs exp2/pack VALU), the m191-attn case (+4-7%).
// ---------------------------------------------------------------------------
__global__ __launch_bounds__(256, 3) void k_attn(
        const unsigned short* __restrict__ qs, const unsigned short* __restrict__ ks,
        const unsigned short* __restrict__ vt, float* __restrict__ out) {
    __shared__ unsigned short Kt[2][128 * 64];     // 32 KB [key][d], sigma+granule swizzle
    __shared__ unsigned short Vt[64 * 128];        // 16 KB [d][key], granule swizzle
    const int t = threadIdx.x;
    const int lane = t & 63, w = t >> 6;
    const int lc = lane & 31, h = lane >> 5;
    // XCD-aware decode: same (b,p) for 8 consecutive blocks on one XCD
    const int gid = blockIdx.x;
    const int g = gid >> 3;
    const int bp_ = (gid & 7) * 32 + (g >> 3);
    const int qt = g & 7;
    const size_t bp = (size_t)bp_;
    const int b = bp_ >> 3, p = bp_ & 7;
    const unsigned short* kbase = ks + bp * NPIX * HD;
    const unsigned short* vbase = vt + bp * HD * NPIX;

    // staging addresses (global side carries sigma + granule swizzle)
    const int krow = t >> 3;
    const int ksig = (((krow >> 2) ^ (krow >> 3)) & 1) ? 12 : 0;
    const int skrow = krow ^ ksig;                       // sigma source row
    const int koff = (((t & 7) ^ (krow & 7)) * 16);
    const int vrow = t >> 4;
    const int voff = (((t & 15) ^ (vrow & 7)) * 16);
    const int lsw = lc & 7;                              // read-side swizzle key

    // Q fragments direct from global: B[n=qrow=w*32+lc][k=h*8+j] per d-chunk
    const unsigned short* qrp = qs + (bp * NPIX + qt * 128 + w * 32 + lc) * HD;
    bf16x8 qf[4];
#pragma unroll
    for (int dk = 0; dk < 4; ++dk)
        qf[dk] = *reinterpret_cast<const bf16x8*>(qrp + dk * 16 + h * 8);

    // ones B-fragment for the denominator MFMA (bf16 1.0 = 0x3f80)
    FragCast ones;
    ones.i[0] = 0x3f803f80; ones.i[1] = 0x3f803f80;
    ones.i[2] = 0x3f803f80; ones.i[3] = 0x3f803f80;

    // prologue: stage K(0)
#pragma unroll
    for (int j = 0; j < 4; ++j)
        gl_lds16((const char*)kbase + (skrow + j * 32) * 128 + koff,
                 (char*)Kt[0] + j * 4096 + w * 1024);
    asm volatile("s_waitcnt vmcnt(0)" ::: "memory");
    __syncthreads();

    f32x16 oacc[2];
    oacc[0] = (f32x16)(0.f);
    oacc[1] = (f32x16)(0.f);
    f32x16 lacc = (f32x16)(0.f);

    for (int kt = 0; kt < 8; ++kt) {
        const int cur = kt & 1;
        // stage V(kt) into the single V buffer (all waves past prior barrier)
#pragma unroll
        for (int j = 0; j < 4; ++j)
            gl_lds16((const char*)vbase + (vrow + j * 16) * 2048 + kt * 256 + voff,
                     (char*)Vt + j * 4096 + w * 1024);
        if (kt < 7) {   // prefetch K(kt+1)
            const int nxt = cur ^ 1;
#pragma unroll
            for (int j = 0; j < 4; ++j)
                gl_lds16((const char*)kbase + (kt + 1) * 16384 + (skrow + j * 32) * 128 + koff,
                         (char*)Kt[nxt] + j * 4096 + w * 1024);
        }

        // ---- S^T = K'.Q^T per 32-key tile, exp2, pack ---------------------
        unsigned pk[4][8];
#pragma unroll
        for (int T = 0; T < 4; ++T) {
            f32x16 s = (f32x16)(0.f);
            const int krb = (T * 32 + lc) * 64;
            __builtin_amdgcn_s_setprio(1);
#pragma unroll
            for (int dk = 0; dk < 4; ++dk) {
                bf16x8 ak = *reinterpret_cast<const bf16x8*>(
                    &Kt[cur][krb + (((dk * 2 + h) ^ lsw) * 8)]);
                s = __builtin_amdgcn_mfma_f32_32x32x16_bf16(ak, qf[dk], s, 0, 0, 0);
            }
            __builtin_amdgcn_s_setprio(0);
            float e[16];
#pragma unroll
            for (int r = 0; r < 16; ++r) e[r] = __builtin_amdgcn_exp2f(s[r]);
#pragma unroll
            for (int j = 0; j < 8; ++j) pk[T][j] = pkbf_fast(e[2 * j], e[2 * j + 1]);
        }

        // wait own V loads (4 newest-issued K may stay outstanding), sync
        if (kt < 7) { asm volatile("s_waitcnt vmcnt(4)" ::: "memory"); }
        else        { asm volatile("s_waitcnt vmcnt(0)" ::: "memory"); }
        __syncthreads();

        // ---- PV: A-frag = lane's own pk registers (sigma made it so) ------
        // lacc accumulates P * ones == per-q-row softmax denominator, in the
        // exact same D-register layout as oacc.
        __builtin_amdgcn_s_setprio(1);
#pragma unroll
        for (int c = 0; c < 8; ++c) {
            FragCast fa;
            fa.i[0] = (int)pk[c >> 1][(c & 1) * 4 + 0];
            fa.i[1] = (int)pk[c >> 1][(c & 1) * 4 + 1];
            fa.i[2] = (int)pk[c >> 1][(c & 1) * 4 + 2];
            fa.i[3] = (int)pk[c >> 1][(c & 1) * 4 + 3];
            const int gv = ((c * 2 + h) ^ lsw) * 8;
#pragma unroll
            for (int nt = 0; nt < 2; ++nt) {
                bf16x8 bv = *reinterpret_cast<const bf16x8*>(
                    &Vt[(nt * 32 + lc) * 128 + gv]);
                oacc[nt] = __builtin_amdgcn_mfma_f32_32x32x16_bf16(
                    fa.v, bv, oacc[nt], 0, 0, 0);
            }
            lacc = __builtin_amdgcn_mfma_f32_32x32x16_bf16(fa.v, ones.v, lacc, 0, 0, 0);
        }
        __builtin_amdgcn_s_setprio(0);

        if (kt < 7) {   // K(kt+1) landed for all waves; V readers done
            asm volatile("s_waitcnt vmcnt(0)" ::: "memory");
            __syncthreads();
        }
    }

    // ---- normalize + store: linv comes straight from lacc (row-aligned) ---
#pragma unroll
    for (int nt = 0; nt < 2; ++nt) {
        const int d = nt * 32 + lc;
        float* ob = out + ((size_t)(b * DIM + p * HD + d)) * NPIX + qt * 128 + w * 32;
#pragma unroll
        for (int gg = 0; gg < 4; ++gg) {
            float4 o4;
            o4.x = oacc[nt][4 * gg + 0] * __builtin_amdgcn_rcpf(lacc[4 * gg + 0]);
            o4.y = oacc[nt][4 * gg + 1] * __builtin_amdgcn_rcpf(lacc[4 * gg + 1]);
            o4.z = oacc[nt][4 * gg + 2] * __builtin_amdgcn_rcpf(lacc[4 * gg + 2]);
            o4.w = oacc[nt][4 * gg + 3] * __builtin_amdgcn_rcpf(lacc[4 * gg + 3]);
            *(float4*)(ob + 8 * gg + 4 * h) = o4;
        }
    }
}

// ---------------------------------------------------------------------------
extern "C" void kernel_launch(void* const* d_in, const int* in_sizes, int n_in,
                              void* d_out, int out_size, void* d_ws, size_t ws_size,
                              hipStream_t stream) {
    const float* x    = (const float*)d_in[0];
    const float* wq   = (const float*)d_in[1];
    const float* bias = (const float*)d_in[2];
    const float* hrel = (const float*)d_in[3];
    const float* wrel = (const float*)d_in[4];
    float* out = (float*)d_out;

    char* ws = (char*)d_ws;
    unsigned short* qs  = (unsigned short*)(ws);                 // 32 MB [b][p][n][d]
    unsigned short* ks  = (unsigned short*)(ws + 33554432u);     // 32 MB [b][p][n][d]
    unsigned short* vt  = (unsigned short*)(ws + 67108864u);     // 32 MB [b][p][d][n]
    unsigned short* xt  = (unsigned short*)d_out;                // 32 MB [b][n][c]
    unsigned short* wqb = (unsigned short*)((char*)d_out + 33554432u);  // 1.5 MB

    k_prep_w<<<dim3(768), 256, 0, stream>>>(wq, wqb);
    k_transpose<<<dim3(16, 8, 32), 256, 0, stream>>>(x, xt);
    k_qkv<<<dim3(3072), 256, 0, stream>>>(xt, wqb, bias, hrel, wrel, qs, ks, vt);
    k_attn<<<dim3(2048), 256, 0, stream>>>(qs, ks, vt, out);
}